// Round 3
// baseline (912.941 us; speedup 1.0000x reference)
//
#include <hip/hip_runtime.h>
#include <hip/hip_bf16.h>

#define NNODES 100000
#define NEDGES 3200000
#define NFEAT  512
#define NHID   16
#define NCLS   64
#define SCAN_NB 391   // ceil(NNODES/256)

typedef short bf16x8 __attribute__((ext_vector_type(8)));
typedef float f32x4  __attribute__((ext_vector_type(4)));

__device__ __forceinline__ short f2bf(float f) {
    unsigned u = __float_as_uint(f);
    return (short)((u + 0x7FFFu + ((u >> 16) & 1u)) >> 16);
}

// ---- degree histogram over real edges (self-loop handled analytically)
__global__ void k_deg(const int* __restrict__ dst, unsigned* __restrict__ cnt) {
    int e = blockIdx.x * blockDim.x + threadIdx.x;
    if (e < NEDGES) atomicAdd(&cnt[dst[e]], 1u);
}

// ---- exclusive scan of cnt -> offs (3 kernels), + dinv, + cursor copy
__global__ void k_scan1(const unsigned* __restrict__ cnt, unsigned* __restrict__ part,
                        unsigned* __restrict__ bsum) {
    __shared__ unsigned s[256];
    int t = threadIdx.x, i = blockIdx.x * 256 + t;
    s[t] = (i < NNODES) ? cnt[i] : 0u;
    __syncthreads();
#pragma unroll
    for (int off = 1; off < 256; off <<= 1) {
        unsigned u = (t >= off) ? s[t - off] : 0u;
        __syncthreads();
        s[t] += u;
        __syncthreads();
    }
    if (i < NNODES) part[i] = s[t];          // inclusive within block
    if (t == 255) bsum[blockIdx.x] = s[255];
}

__global__ void k_scan2(unsigned* __restrict__ bsum) {
    __shared__ unsigned s[512];
    int t = threadIdx.x;
    s[t] = (t < SCAN_NB) ? bsum[t] : 0u;
    __syncthreads();
#pragma unroll
    for (int off = 1; off < 512; off <<= 1) {
        unsigned u = (t >= off) ? s[t - off] : 0u;
        __syncthreads();
        s[t] += u;
        __syncthreads();
    }
    if (t < SCAN_NB) bsum[t] = s[t];         // inclusive block sums
}

__global__ void k_scan3(const unsigned* __restrict__ cnt, const unsigned* __restrict__ part,
                        const unsigned* __restrict__ bsum, unsigned* __restrict__ offs,
                        unsigned* __restrict__ cursor, float* __restrict__ dinv) {
    int i = blockIdx.x * 256 + threadIdx.x;
    if (i >= NNODES) return;
    int b = blockIdx.x;
    unsigned e = part[i] - cnt[i] + (b > 0 ? bsum[b - 1] : 0u);
    offs[i] = e;
    cursor[i] = e;
    dinv[i] = rsqrtf((float)(cnt[i] + 1u));  // +1 = self-loop
}

// ---- bin edges by dst: eb[] holds src indices grouped by dst (norm folded out)
__global__ void k_bin(const int* __restrict__ src, const int* __restrict__ dst,
                      unsigned* __restrict__ cursor, int* __restrict__ eb) {
    int e = blockIdx.x * blockDim.x + threadIdx.x;
    if (e >= NEDGES) return;
    unsigned pos = atomicAdd(&cursor[dst[e]], 1u);
    eb[pos] = src[e];
}

// ---- hs1 = (x @ W1) * dinv[row]  (bf16 MFMA inside; dinv pre-scaled rows)
__global__ __launch_bounds__(256) void k_gemm1(const float* __restrict__ x,
                                               const float* __restrict__ w1,
                                               const float* __restrict__ dinv,
                                               float* __restrict__ hs1) {
    __shared__ short w1t[16][520];   // W1^T as bf16, +8 pad
    int tid = threadIdx.x;
    for (int idx = tid; idx < NFEAT * NHID; idx += 256) {
        int k = idx >> 4, n = idx & 15;
        w1t[n][k] = f2bf(w1[idx]);
    }
    __syncthreads();
    int wave = tid >> 6, lane = tid & 63;
    int tile = blockIdx.x * 4 + wave;
    if (tile >= NNODES / 16) return;           // 6250 tiles exactly
    int m = lane & 15, q = lane >> 4;
    const float* xrow = x + (size_t)(tile * 16 + m) * NFEAT + q * 8;
    const short* wrow = &w1t[m][q * 8];
    f32x4 acc = {0.f, 0.f, 0.f, 0.f};
#pragma unroll
    for (int kb = 0; kb < NFEAT / 32; ++kb) {
        float4 a0 = *(const float4*)(xrow + kb * 32);
        float4 a1 = *(const float4*)(xrow + kb * 32 + 4);
        bf16x8 a;
        a[0] = f2bf(a0.x); a[1] = f2bf(a0.y); a[2] = f2bf(a0.z); a[3] = f2bf(a0.w);
        a[4] = f2bf(a1.x); a[5] = f2bf(a1.y); a[6] = f2bf(a1.z); a[7] = f2bf(a1.w);
        bf16x8 b = *(const bf16x8*)(wrow + kb * 32);
        acc = __builtin_amdgcn_mfma_f32_16x16x32_bf16(a, b, acc, 0, 0, 0);
    }
    // C/D: col = lane&15, row = (lane>>4)*4 + r   [m89-verified]
    float* out = hs1 + (size_t)(tile * 16) * NHID;
#pragma unroll
    for (int r = 0; r < 4; ++r) {
        int row = q * 4 + r;
        out[row * NHID + m] = acc[r] * dinv[tile * 16 + row];
    }
}

// ---- layer-1 aggregate (gather) + self-loop + bias + relu; output pre-scaled by dinv
__global__ __launch_bounds__(256) void k_agg1(const unsigned* __restrict__ offs,
                                              const unsigned* __restrict__ cnt,
                                              const int* __restrict__ eb,
                                              const float* __restrict__ hs1,
                                              const float* __restrict__ dinv,
                                              const float* __restrict__ b1,
                                              float* __restrict__ hs2) {
    int tid = threadIdx.x;
    int node = blockIdx.x * 4 + (tid >> 6);    // 25000*4 = 100000 exact
    int lane = tid & 63, f = lane & 15, slot = lane >> 4;
    unsigned start = offs[node];
    int deg = (int)cnt[node];
    float acc = 0.f;
    for (int j = slot; j < deg; j += 4)
        acc += hs1[(size_t)eb[start + j] * NHID + f];   // weights folded into hs1
    acc += __shfl_xor(acc, 16);
    acc += __shfl_xor(acc, 32);
    float di = dinv[node];
    float v = (acc + hs1[(size_t)node * NHID + f]) * di + b1[f];
    v = v > 0.f ? v : 0.f;
    if (slot == 0) hs2[(size_t)node * NHID + f] = v * di;  // pre-scale for layer 2
}

// ---- layer-2 aggregate (gather) + self-loop + W2 matvec + b2 + log_softmax
__global__ __launch_bounds__(256) void k_out2(const unsigned* __restrict__ offs,
                                              const unsigned* __restrict__ cnt,
                                              const int* __restrict__ eb,
                                              const float* __restrict__ hs2,
                                              const float* __restrict__ dinv,
                                              const float* __restrict__ w2,
                                              const float* __restrict__ b2,
                                              float* __restrict__ out) {
    __shared__ float w2f[NHID * NCLS];
    __shared__ float b2f[NCLS];
    int tid = threadIdx.x;
    for (int i = tid; i < NHID * NCLS; i += 256) w2f[i] = w2[i];
    if (tid < NCLS) b2f[tid] = b2[tid];
    __syncthreads();
    int node = blockIdx.x * 4 + (tid >> 6);
    int lane = tid & 63, f = lane & 15, slot = lane >> 4;
    unsigned start = offs[node];
    int deg = (int)cnt[node];
    float acc = 0.f;
    for (int j = slot; j < deg; j += 4)
        acc += hs2[(size_t)eb[start + j] * NHID + f];
    acc += __shfl_xor(acc, 16);
    acc += __shfl_xor(acc, 32);
    float di = dinv[node];
    float v = (acc + hs2[(size_t)node * NHID + f]) * di;   // v16 component f (all lanes)
    float logit = b2f[lane];
#pragma unroll
    for (int k = 0; k < NHID; ++k)
        logit += __shfl(v, k) * w2f[k * NCLS + lane];      // lane k holds f=k
    float mx = logit;
#pragma unroll
    for (int off = 32; off > 0; off >>= 1) mx = fmaxf(mx, __shfl_xor(mx, off));
    float ex = __expf(logit - mx);
    float s = ex;
#pragma unroll
    for (int off = 32; off > 0; off >>= 1) s += __shfl_xor(s, off);
    out[(size_t)node * NCLS + lane] = logit - mx - logf(s);
}

extern "C" void kernel_launch(void* const* d_in, const int* in_sizes, int n_in,
                              void* d_out, int out_size, void* d_ws, size_t ws_size,
                              hipStream_t stream) {
    const float* x  = (const float*)d_in[0];   // f32 [100000,512]
    const int*   ei = (const int*)d_in[1];     // int32 [2,3200000]
    const float* w1 = (const float*)d_in[2];   // f32 [512,16]
    const float* b1 = (const float*)d_in[3];   // f32 [16]
    const float* w2 = (const float*)d_in[4];   // f32 [16,64]
    const float* b2 = (const float*)d_in[5];   // f32 [64]
    const int* src = ei;
    const int* dst = ei + NEDGES;

    char* ws = (char*)d_ws;
    unsigned* cnt    = (unsigned*)(ws + 0);          //   400,000 B
    unsigned* part   = (unsigned*)(ws + 400000);     //   400,000 B (cursor aliases after scan)
    unsigned* bsum   = (unsigned*)(ws + 800000);     //     2,048 B
    unsigned* offs   = (unsigned*)(ws + 802048);     //   400,000 B
    float*    dinv   = (float*)   (ws + 1202048);    //   400,000 B
    float*    hs1    = (float*)   (ws + 1602048);    // 6,400,000 B
    float*    hs2    = (float*)   (ws + 8002048);    // 6,400,000 B
    int*      eb     = (int*)     (ws + 14402048);   // 12,800,000 B  (total 27.2 MB)
    unsigned* cursor = part;                         // part dead after k_scan3

    hipMemsetAsync(cnt, 0, 400000, stream);
    k_deg  <<<(NEDGES + 255) / 256, 256, 0, stream>>>(dst, cnt);
    k_scan1<<<SCAN_NB, 256, 0, stream>>>(cnt, part, bsum);
    k_scan2<<<1, 512, 0, stream>>>(bsum);
    k_scan3<<<SCAN_NB, 256, 0, stream>>>(cnt, part, bsum, offs, cursor, dinv);
    k_bin  <<<(NEDGES + 255) / 256, 256, 0, stream>>>(src, dst, cursor, eb);
    k_gemm1<<<(NNODES / 16 + 3) / 4, 256, 0, stream>>>(x, w1, dinv, hs1);
    k_agg1 <<<NNODES / 4, 256, 0, stream>>>(offs, cnt, eb, hs1, dinv, b1, hs2);
    k_out2 <<<NNODES / 4, 256, 0, stream>>>(offs, cnt, eb, hs2, dinv, w2, b2, (float*)d_out);
}

// Round 4
// 558.715 us; speedup vs baseline: 1.6340x; 1.6340x over previous
//
#include <hip/hip_runtime.h>

#define NNODES 100000
#define NEDGES 3200000
#define NFEAT  512
#define NHID   16
#define NCLS   64
#define NB     391      // ceil(100000/256) buckets of 256 nodes (bucket = dst>>8)
#define CAP    10240    // per-bucket edge capacity (mean 8192, sd ~90 -> +22 sigma)
#define EPB    8192     // edges per block in pass A

typedef short bf16x8 __attribute__((ext_vector_type(8)));
typedef float f32x4  __attribute__((ext_vector_type(4)));

__device__ __forceinline__ short f2bf(float f) {
    unsigned u = __float_as_uint(f);
    return (short)((u + 0x7FFFu + ((u >> 16) & 1u)) >> 16);
}

// ---- pass A: partition edges into 391 coarse buckets, LDS-staged coalesced writes
__global__ __launch_bounds__(256) void k_part(const int* __restrict__ src,
                                              const int* __restrict__ dst,
                                              unsigned* __restrict__ gcnt,
                                              unsigned* __restrict__ part) {
    __shared__ unsigned hist[NB];
    __shared__ unsigned scn[512];
    __shared__ unsigned cursor[NB];
    __shared__ unsigned delta[NB];
    __shared__ unsigned staged[EPB];
    __shared__ unsigned short pbkt[EPB];
    int t = threadIdx.x;
    int base = blockIdx.x * EPB;
    int nblk = min(EPB, NEDGES - base);
    for (int i = t; i < NB; i += 256) hist[i] = 0;
    __syncthreads();
    unsigned pk[32]; unsigned short bk[32];
#pragma unroll
    for (int j = 0; j < 32; ++j) {
        int o = t + j * 256;
        if (o < nblk) {
            int s = src[base + o], d = dst[base + o];
            pk[j] = (unsigned)s | ((unsigned)(d & 255) << 17);
            bk[j] = (unsigned short)(d >> 8);
            atomicAdd(&hist[bk[j]], 1u);
        } else bk[j] = 0xFFFFu;
    }
    __syncthreads();
    // inclusive scan of hist (padded to 512) — each thread owns slots t, t+256
    scn[t] = (t < NB) ? hist[t] : 0u;
    scn[t + 256] = (t + 256 < NB) ? hist[t + 256] : 0u;
    __syncthreads();
#pragma unroll
    for (int off = 1; off < 512; off <<= 1) {
        unsigned a = (t >= off) ? scn[t - off] : 0u;
        unsigned b = (t + 256 >= off) ? scn[t + 256 - off] : 0u;
        __syncthreads();
        scn[t] += a; scn[t + 256] += b;
        __syncthreads();
    }
    // reserve global ranges: one atomic per (block,bucket)
    for (int i = t; i < NB; i += 256) {
        unsigned h = hist[i];
        unsigned ex = scn[i] - h;                       // exclusive local start
        cursor[i] = ex;
        unsigned gb = h ? atomicAdd(&gcnt[i], h) : 0u;
        delta[i] = (unsigned)i * CAP + gb - ex;
    }
    __syncthreads();
    // stage bucket-major in LDS
#pragma unroll
    for (int j = 0; j < 32; ++j) {
        if (bk[j] != 0xFFFFu) {
            unsigned p = atomicAdd(&cursor[bk[j]], 1u);
            staged[p] = pk[j];
            pbkt[p] = bk[j];
        }
    }
    __syncthreads();
    // stream out: contiguous runs per bucket
    for (int i = t; i < nblk; i += 256) {
        unsigned b = pbkt[i];
        unsigned d = delta[b] + (unsigned)i;
        if (d < (b + 1u) * CAP) part[d] = staged[i];    // overflow guard (p~1e-100)
    }
}

// ---- pass B: per-bucket fine CSR (degree, offsets, dinv) + in-place sorted rewrite
__global__ __launch_bounds__(256) void k_csr(const unsigned* __restrict__ gcnt,
                                             unsigned* __restrict__ part,
                                             unsigned* __restrict__ offs,
                                             unsigned* __restrict__ cnt,
                                             float* __restrict__ dinv) {
    __shared__ unsigned hist[256], nst[256], cursor[256];
    __shared__ unsigned staged[CAP];
    int t = threadIdx.x, b = blockIdx.x;
    unsigned cb = min(gcnt[b], (unsigned)CAP);
    unsigned* seg = part + (size_t)b * CAP;
    hist[t] = 0;
    __syncthreads();
    for (unsigned i = t; i < cb; i += 256)
        atomicAdd(&hist[(seg[i] >> 17) & 255u], 1u);
    __syncthreads();
    nst[t] = hist[t];
    __syncthreads();
#pragma unroll
    for (int off = 1; off < 256; off <<= 1) {
        unsigned a = (t >= off) ? nst[t - off] : 0u;
        __syncthreads();
        nst[t] += a;
        __syncthreads();
    }
    unsigned ex = nst[t] - hist[t];
    cursor[t] = ex;
    int node = b * 256 + t;
    if (node < NNODES) {
        offs[node] = (unsigned)b * CAP + ex;
        cnt[node] = hist[t];
        dinv[node] = rsqrtf((float)hist[t] + 1.f);      // +1 = self-loop
    }
    __syncthreads();
    for (unsigned i = t; i < cb; i += 256) {
        unsigned p = seg[i];
        unsigned r = atomicAdd(&cursor[(p >> 17) & 255u], 1u);
        staged[r] = p & 0x1FFFFu;                       // src only
    }
    __syncthreads();
    for (unsigned i = t; i < cb; i += 256)
        seg[i] = staged[i];                             // coalesced in-place rewrite
}

// ---- hs1 = (x @ W1) * dinv[row]  (bf16 MFMA inside)
__global__ __launch_bounds__(256) void k_gemm1(const float* __restrict__ x,
                                               const float* __restrict__ w1,
                                               const float* __restrict__ dinv,
                                               float* __restrict__ hs1) {
    __shared__ short w1t[16][520];
    int tid = threadIdx.x;
    for (int idx = tid; idx < NFEAT * NHID; idx += 256) {
        int k = idx >> 4, n = idx & 15;
        w1t[n][k] = f2bf(w1[idx]);
    }
    __syncthreads();
    int wave = tid >> 6, lane = tid & 63;
    int tile = blockIdx.x * 4 + wave;
    if (tile >= NNODES / 16) return;
    int m = lane & 15, q = lane >> 4;
    const float* xrow = x + (size_t)(tile * 16 + m) * NFEAT + q * 8;
    const short* wrow = &w1t[m][q * 8];
    f32x4 acc = {0.f, 0.f, 0.f, 0.f};
#pragma unroll
    for (int kb = 0; kb < NFEAT / 32; ++kb) {
        float4 a0 = *(const float4*)(xrow + kb * 32);
        float4 a1 = *(const float4*)(xrow + kb * 32 + 4);
        bf16x8 a;
        a[0] = f2bf(a0.x); a[1] = f2bf(a0.y); a[2] = f2bf(a0.z); a[3] = f2bf(a0.w);
        a[4] = f2bf(a1.x); a[5] = f2bf(a1.y); a[6] = f2bf(a1.z); a[7] = f2bf(a1.w);
        bf16x8 b = *(const bf16x8*)(wrow + kb * 32);
        acc = __builtin_amdgcn_mfma_f32_16x16x32_bf16(a, b, acc, 0, 0, 0);
    }
    float* out = hs1 + (size_t)(tile * 16) * NHID;
#pragma unroll
    for (int r = 0; r < 4; ++r) {
        int row = q * 4 + r;
        out[row * NHID + m] = acc[r] * dinv[tile * 16 + row];
    }
}

// ---- layer-1 aggregate (gather) + self-loop + bias + relu; output pre-scaled by dinv
__global__ __launch_bounds__(256) void k_agg1(const unsigned* __restrict__ offs,
                                              const unsigned* __restrict__ cnt,
                                              const unsigned* __restrict__ eb,
                                              const float* __restrict__ hs1,
                                              const float* __restrict__ dinv,
                                              const float* __restrict__ b1,
                                              float* __restrict__ hs2) {
    int tid = threadIdx.x;
    int node = blockIdx.x * 4 + (tid >> 6);
    int lane = tid & 63, f = lane & 15, slot = lane >> 4;
    unsigned start = offs[node];
    int deg = (int)cnt[node];
    float acc = 0.f;
    for (int j = slot; j < deg; j += 4)
        acc += hs1[(size_t)eb[start + j] * NHID + f];
    acc += __shfl_xor(acc, 16);
    acc += __shfl_xor(acc, 32);
    float di = dinv[node];
    float v = (acc + hs1[(size_t)node * NHID + f]) * di + b1[f];
    v = v > 0.f ? v : 0.f;
    if (slot == 0) hs2[(size_t)node * NHID + f] = v * di;
}

// ---- layer-2 aggregate + self-loop + W2 matvec + b2 + log_softmax
__global__ __launch_bounds__(256) void k_out2(const unsigned* __restrict__ offs,
                                              const unsigned* __restrict__ cnt,
                                              const unsigned* __restrict__ eb,
                                              const float* __restrict__ hs2,
                                              const float* __restrict__ dinv,
                                              const float* __restrict__ w2,
                                              const float* __restrict__ b2,
                                              float* __restrict__ out) {
    __shared__ float w2f[NHID * NCLS];
    __shared__ float b2f[NCLS];
    int tid = threadIdx.x;
    for (int i = tid; i < NHID * NCLS; i += 256) w2f[i] = w2[i];
    if (tid < NCLS) b2f[tid] = b2[tid];
    __syncthreads();
    int node = blockIdx.x * 4 + (tid >> 6);
    int lane = tid & 63, f = lane & 15, slot = lane >> 4;
    unsigned start = offs[node];
    int deg = (int)cnt[node];
    float acc = 0.f;
    for (int j = slot; j < deg; j += 4)
        acc += hs2[(size_t)eb[start + j] * NHID + f];
    acc += __shfl_xor(acc, 16);
    acc += __shfl_xor(acc, 32);
    float di = dinv[node];
    float v = (acc + hs2[(size_t)node * NHID + f]) * di;
    float logit = b2f[lane];
#pragma unroll
    for (int k = 0; k < NHID; ++k)
        logit += __shfl(v, k) * w2f[k * NCLS + lane];
    float mx = logit;
#pragma unroll
    for (int off = 32; off > 0; off >>= 1) mx = fmaxf(mx, __shfl_xor(mx, off));
    float ex = __expf(logit - mx);
    float s = ex;
#pragma unroll
    for (int off = 32; off > 0; off >>= 1) s += __shfl_xor(s, off);
    out[(size_t)node * NCLS + lane] = logit - mx - logf(s);
}

extern "C" void kernel_launch(void* const* d_in, const int* in_sizes, int n_in,
                              void* d_out, int out_size, void* d_ws, size_t ws_size,
                              hipStream_t stream) {
    const float* x  = (const float*)d_in[0];   // f32 [100000,512]
    const int*   ei = (const int*)d_in[1];     // int32 [2,3200000]
    const float* w1 = (const float*)d_in[2];   // f32 [512,16]
    const float* b1 = (const float*)d_in[3];   // f32 [16]
    const float* w2 = (const float*)d_in[4];   // f32 [16,64]
    const float* b2 = (const float*)d_in[5];   // f32 [64]
    const int* src = ei;
    const int* dst = ei + NEDGES;

    char* ws = (char*)d_ws;
    unsigned* gcnt = (unsigned*)(ws + 0);          //     2,048 B
    unsigned* offs = (unsigned*)(ws + 2048);       //   400,000 B
    unsigned* cnt  = (unsigned*)(ws + 402048);     //   400,000 B
    float*    dinv = (float*)   (ws + 802048);     //   400,000 B
    float*    hs1  = (float*)   (ws + 1202048);    // 6,400,000 B
    float*    hs2  = (float*)   (ws + 7602048);    // 6,400,000 B
    unsigned* part = (unsigned*)(ws + 14002048);   // 16,015,360 B (total ~30 MB)

    hipMemsetAsync(gcnt, 0, 2048, stream);
    k_part <<<NB, 256, 0, stream>>>(src, dst, gcnt, part);
    k_csr  <<<NB, 256, 0, stream>>>(gcnt, part, offs, cnt, dinv);
    k_gemm1<<<(NNODES / 16 + 3) / 4, 256, 0, stream>>>(x, w1, dinv, hs1);
    k_agg1 <<<NNODES / 4, 256, 0, stream>>>(offs, cnt, part, hs1, dinv, b1, hs2);
    k_out2 <<<NNODES / 4, 256, 0, stream>>>(offs, cnt, part, hs2, dinv, w2, b2, (float*)d_out);
}